// Round 3
// baseline (237.874 us; speedup 1.0000x reference)
//
#include <hip/hip_runtime.h>
#include <hip/hip_bf16.h>

// out[b,s] = cumsum_s( softplus(beta * c[b,s]) / beta ), fp32, B=4096, S=8192.
//
// R3: R2's register-resident block scan (coalesced float4 both ends, 256 B
// LDS, one barrier/row) + SOFTWARE PIPELINING OVER ROWS. R2 showed the
// phases execute convoy-style (HBM busy 51%, VALU 30%, both idle half the
// time, dur unchanged at 82 us despite occupancy x2). Each block now owns
// RPB=4 rows (row = blockIdx.x + k*gridDim.x) and prefetches row k+1 into a
// second register buffer BEFORE computing row k, so the loads are in flight
// across the softplus+scan phase and are complete by the barrier's vmcnt
// drain. wave_sums is parity-double-buffered so one barrier per row suffices.

#define ROW_S   8192
#define BLOCK_T 256
#define NJ      (ROW_S / 4 / BLOCK_T)   // 8 float4 chunks per thread per row
#define NWAVE   (BLOCK_T / 64)          // 4 waves per block
#define RPB     4                       // rows per block (pipeline depth)

__device__ __forceinline__ float softplus_step(float c, float beta, float inv_beta) {
    float tb = beta * c;
    float e  = __expf(-fabsf(tb));     // in (0,1], no overflow
    float l  = __logf(1.0f + e);       // log1p(exp(-|t|))
    return (fmaxf(tb, 0.0f) + l) * inv_beta;
}

__global__ __launch_bounds__(BLOCK_T, 4) void softplus_cumsum_kernel(
    const float* __restrict__ c,
    const float* __restrict__ beta_p,
    float* __restrict__ out,
    int nrows)
{
    __shared__ float wave_sums[2][NJ][NWAVE];   // 256 B, parity double-buffered

    const int t    = threadIdx.x;
    const int lane = t & 63;
    const int wave = t >> 6;

    const float beta     = beta_p[0];
    const float inv_beta = 1.0f / beta;

    // Prefetch row 0 into va.
    float4 va[NJ], vb[NJ];
    {
        const size_t row0 = blockIdx.x;
        if ((int)row0 < nrows) {
            const float4* in4 = (const float4*)c + row0 * (ROW_S / 4);
            #pragma unroll
            for (int j = 0; j < NJ; ++j) va[j] = in4[j * BLOCK_T + t];
        }
    }

    #pragma unroll
    for (int k = 0; k < RPB; ++k) {
        const size_t row = (size_t)blockIdx.x + (size_t)k * gridDim.x;
        if ((int)row >= nrows) break;           // uniform across block

        // ---- issue prefetch of row k+1 FIRST (overlaps all of row k's work)
        const size_t nrow = (size_t)blockIdx.x + (size_t)(k + 1) * gridDim.x;
        if (k + 1 < RPB && (int)nrow < nrows) {
            const float4* nin4 = (const float4*)c + nrow * (ROW_S / 4);
            #pragma unroll
            for (int j = 0; j < NJ; ++j) vb[j] = nin4[j * BLOCK_T + t];
        }

        // ---- softplus + in-chunk (4-elem) inclusive scan on current buffer
        float4 r[NJ];
        float  s[NJ];
        #pragma unroll
        for (int j = 0; j < NJ; ++j) {
            float a = softplus_step(va[j].x, beta, inv_beta);
            float b = softplus_step(va[j].y, beta, inv_beta);
            float d = softplus_step(va[j].z, beta, inv_beta);
            float e = softplus_step(va[j].w, beta, inv_beta);
            r[j].x = a;
            r[j].y = a + b;
            r[j].z = r[j].y + d;
            r[j].w = r[j].z + e;
            s[j]   = r[j].w;
        }

        // ---- 8 independent wave-inclusive shuffle scans of chunk sums
        float excl[NJ];
        #pragma unroll
        for (int j = 0; j < NJ; ++j) {
            float x = s[j];
            #pragma unroll
            for (int d = 1; d < 64; d <<= 1) {
                float y = __shfl_up(x, d, 64);
                if (lane >= d) x += y;
            }
            excl[j] = x - s[j];                 // exclusive within wave
            if (lane == 63) wave_sums[k & 1][j][wave] = x;
        }
        __syncthreads();

        // ---- combine carries + coalesced store from registers
        float4* out4 = (float4*)out + row * (ROW_S / 4);
        float carry = 0.0f;
        #pragma unroll
        for (int j = 0; j < NJ; ++j) {
            float woff = 0.0f, btot = 0.0f;
            #pragma unroll
            for (int w = 0; w < NWAVE; ++w) {
                float ws = wave_sums[k & 1][j][w];   // broadcast read
                if (w < wave) woff += ws;            // wave-uniform predicate
                btot += ws;
            }
            const float off = carry + woff + excl[j];
            carry += btot;
            float4 o;
            o.x = r[j].x + off;
            o.y = r[j].y + off;
            o.z = r[j].z + off;
            o.w = r[j].w + off;
            out4[j * BLOCK_T + t] = o;
        }

        // ---- rotate buffers: prefetched row becomes current
        #pragma unroll
        for (int j = 0; j < NJ; ++j) va[j] = vb[j];
    }
}

extern "C" void kernel_launch(void* const* d_in, const int* in_sizes, int n_in,
                              void* d_out, int out_size, void* d_ws, size_t ws_size,
                              hipStream_t stream) {
    const float* c      = (const float*)d_in[0];
    const float* beta_p = (const float*)d_in[1];
    float*       out    = (float*)d_out;

    const int B = in_sizes[0] / ROW_S;              // 4096 rows
    const int nblocks = (B + RPB - 1) / RPB;        // 1024 blocks, 4 rows each
    softplus_cumsum_kernel<<<dim3(nblocks), dim3(BLOCK_T), 0, stream>>>(
        c, beta_p, out, B);
}